// Round 8
// baseline (56.849 us; speedup 1.0000x reference)
//
#include <hip/hip_runtime.h>

// BEV pooling (Lift-Splat-Shoot) via CSR-style row buckets, MI355X / gfx950.
//
//   x:    flat (Nprime=473088, C=80) f32
//   geom: flat (Nprime, 3) i32
//   out:  (B, C=80, NZ=16, NX=128, NY=128) f32
//   out[b][c][z][x][y] = sum of x[p][c] over in-bounds points p at (x,y,z).
//
// k0: row_cnt[] = 0 (8 KB)
// k1: fill fixed-capacity per-(z,x)-row buckets: pos=atomicAdd(cnt), entry=(p<<7)|y.
//     No linked lists -> gather has NO pointer-chase.
// k2: one block per (z,x) row, 512 threads: ONE coalesced bucket load -> LDS,
//     latency hidden under acc zeroing; process as 25 entry-slots x 20 c-quads
//     (float4 x loads, 320B row per slot, serial-load depth ~1-2); LDS 128x81
//     acc tile; float4 nontemporal coalesced store. No output atomics/memset.

#define BNX 128
#define BNY 128
#define BNZ 16
#define BC  80
#define ACCP 81                    // padded acc stride (bank spread for store phase)
#define PLANE      (BNX * BNY)     // 16384
#define NSEG_PER_B (BNZ * PLANE)   // 262144
#define ZX         (BNZ * BNX)     // 2048 rows per batch
#define KCAP 1024                  // bucket capacity (row mean 27.5, sigma ~5)
#define GT 512                     // gather block size

typedef float fvec4 __attribute__((ext_vector_type(4)));

// ---- kernel 0: row_cnt = 0 -------------------------------------------------
__global__ __launch_bounds__(256) void init_cnt(int* __restrict__ cnt, int n)
{
    int i = blockIdx.x * blockDim.x + threadIdx.x;
    if (i < n) cnt[i] = 0;
}

// ---- kernel 1: fill row buckets -------------------------------------------
__global__ __launch_bounds__(256) void fill_buckets(
    const int* __restrict__ geom,
    int* __restrict__ row_cnt,   // [B*ZX]
    int* __restrict__ plist,     // [B*ZX*KCAP], entries (p<<7)|y
    int npoints, int per_b)
{
    int p = blockIdx.x * blockDim.x + threadIdx.x;
    if (p >= npoints) return;

    int gx = geom[p * 3 + 0];
    int gy = geom[p * 3 + 1];
    int gz = geom[p * 3 + 2];
    if ((unsigned)gx >= (unsigned)BNX ||
        (unsigned)gy >= (unsigned)BNY ||
        (unsigned)gz >= (unsigned)BNZ) return;

    int b   = p / per_b;
    int row = b * ZX + gz * BNX + gx;
    int pos = atomicAdd(&row_cnt[row], 1);
    if (pos < KCAP) plist[(size_t)row * KCAP + pos] = (p << 7) | gy;
}

// ---- kernel 2: row gather --------------------------------------------------
// grid = B*ZX blocks, 512 threads. Block owns (b, z, x): cells y=0..127, all c.
__global__ __launch_bounds__(GT) void gather_rows(
    const float* __restrict__ x,
    const int* __restrict__ plist,
    const int* __restrict__ row_cnt,
    float* __restrict__ out)
{
    __shared__ float acc[BNY * ACCP];   // 41.5 KB
    __shared__ int   list[KCAP];        // 4 KB

    const int tid = threadIdx.x;
    const int row = blockIdx.x;                 // b*ZX + zx
    const int b   = row / ZX;
    const int zx  = row - b * ZX;

    int n = row_cnt[row];
    n = n < KCAP ? n : KCAP;

    // stage bucket entries (ONE coalesced load for typical n~28), then zero
    // the acc tile while the load is in flight.
    for (int i = tid; i < n; i += GT) list[i] = plist[(size_t)row * KCAP + i];
    for (int i = tid; i < BNY * ACCP; i += GT) acc[i] = 0.f;
    __syncthreads();

    // process phase: 25 entry slots x 20 channel-quads. One float4 load per
    // (entry, c-quad); a 320B x row is read by 20 consecutive lanes, once.
    if (tid < 500) {
        const int s  = tid / 20;      // entry slot 0..24
        const int cq = tid % 20;      // channel quad 0..19
        for (int i = s; i < n; i += 25) {
            int e  = list[i];
            int pp = e >> 7;
            int yy = e & 127;
            const fvec4 xv = *reinterpret_cast<const fvec4*>(
                &x[(size_t)pp * BC + cq * 4]);
            float* a = &acc[yy * ACCP + cq * 4];
            atomicAdd(&a[0], xv.x);
            atomicAdd(&a[1], xv.y);
            atomicAdd(&a[2], xv.z);
            atomicAdd(&a[3], xv.w);
        }
    }
    __syncthreads();

    // store phase: float4 per thread; 32 lanes x 16B = one 512B y-row per
    // channel, nontemporal (write-once stream, keep L2/L3 for x + buckets).
    {
        const int l  = tid & 31;          // y-quad: y = 4l..4l+3
        const int c0 = tid >> 5;          // 0..15
        size_t rowbase = (size_t)b * BC * NSEG_PER_B + (size_t)zx * BNY + 4 * l;
        for (int cc = c0; cc < BC; cc += 16) {
            fvec4 v;
            v.x = acc[(4 * l + 0) * ACCP + cc];
            v.y = acc[(4 * l + 1) * ACCP + cc];
            v.z = acc[(4 * l + 2) * ACCP + cc];
            v.w = acc[(4 * l + 3) * ACCP + cc];
            __builtin_nontemporal_store(v,
                (fvec4*)&out[rowbase + (size_t)cc * NSEG_PER_B]);
        }
    }
}

extern "C" void kernel_launch(void* const* d_in, const int* in_sizes, int n_in,
                              void* d_out, int out_size, void* d_ws, size_t ws_size,
                              hipStream_t stream)
{
    const float* x  = (const float*)d_in[0];
    const int* geom = (const int*)d_in[1];
    float* out      = (float*)d_out;

    const int npoints = in_sizes[0] / BC;                 // 473088
    const int B       = out_size / (BC * NSEG_PER_B);     // 1
    const int per_b   = npoints / (B > 0 ? B : 1);
    const int nrows   = B * ZX;                           // 2048

    int* row_cnt = (int*)d_ws;             // [nrows]
    int* plist   = row_cnt + nrows;        // [nrows*KCAP] = 8 MB

    init_cnt<<<(nrows + 255) / 256, 256, 0, stream>>>(row_cnt, nrows);

    fill_buckets<<<(npoints + 255) / 256, 256, 0, stream>>>(
        geom, row_cnt, plist, npoints, per_b);

    gather_rows<<<nrows, GT, 0, stream>>>(x, plist, row_cnt, out);
}